// Round 2
// baseline (4172.626 us; speedup 1.0000x reference)
//
#include <hip/hip_runtime.h>

typedef unsigned short u16;
typedef unsigned int   u32;

__device__ __forceinline__ float bf2f(u16 v) {
    u32 x = ((u32)v) << 16;
    return __builtin_bit_cast(float, x);
}
__device__ __forceinline__ float bflo(u32 u) { return __builtin_bit_cast(float, u << 16); }
__device__ __forceinline__ float bfhi(u32 u) { return __builtin_bit_cast(float, u & 0xffff0000u); }
__device__ __forceinline__ u16 f2bf(float f) {
    u32 x = __builtin_bit_cast(u32, f);
    u32 r = (x + 0x7fffu + ((x >> 16) & 1u)) >> 16;
    return (u16)r;
}
__device__ __forceinline__ float mishf(float x) {
    // x * tanh(softplus(x)) == x * (p^2-1)/(p^2+1), p = 1+e^x
    if (x > 15.f) return x;
    float p = 1.f + __expf(x);
    float q = p * p;
    return x * (q - 1.f) / (q + 1.f);
}

// ---------------------------------------------------------------------------
// fp32-in GEMM: C[M,N] = A[M,K] @ W[K,N], bf16 out.
// mode 0: row-major store. mode 1: per-batch transposed store C_t[b][n][j]
// (b = row/512, j = row%512). Tiles 64x64, K-step 32, 256 thr, 4x4/thread.
// ---------------------------------------------------------------------------
__global__ __launch_bounds__(256) void gemm_f32(
    const float* __restrict__ A, const float* __restrict__ W, u16* __restrict__ C,
    int M, int N, int K, int mode)
{
    __shared__ float As[32][68];   // [k][m], padded
    __shared__ float Ws[32][64];   // [k][n]
    __shared__ u16 Ct[64][72];     // transpose staging (mode 1)

    const int tid = threadIdx.x;
    const int m0 = blockIdx.y * 64, n0 = blockIdx.x * 64;
    const int mt = tid >> 4, nt = tid & 15;

    float acc[4][4] = {};

    for (int k0 = 0; k0 < K; k0 += 32) {
        {   // stage A transposed: 64 rows x 32 k (4 threads/row, 8 k each)
            int r = tid >> 2, q = tid & 3;
            const float* ap = A + (size_t)(m0 + r) * K + k0 + q * 8;
            const float4 a0 = *(const float4*)ap;
            const float4 a1 = *(const float4*)(ap + 4);
            As[q * 8 + 0][r] = a0.x; As[q * 8 + 1][r] = a0.y;
            As[q * 8 + 2][r] = a0.z; As[q * 8 + 3][r] = a0.w;
            As[q * 8 + 4][r] = a1.x; As[q * 8 + 5][r] = a1.y;
            As[q * 8 + 6][r] = a1.z; As[q * 8 + 7][r] = a1.w;
        }
        {   // stage W natural: 32 k-rows x 64 n (8 threads/row, 8 n each)
            int kr = tid >> 3, g = tid & 7;
            const float* wp = W + (size_t)(k0 + kr) * N + n0 + g * 8;
            *(float4*)&Ws[kr][g * 8]     = *(const float4*)wp;
            *(float4*)&Ws[kr][g * 8 + 4] = *(const float4*)(wp + 4);
        }
        __syncthreads();
#pragma unroll
        for (int kk = 0; kk < 32; ++kk) {
            const float4 av = *(const float4*)&As[kk][mt * 4];
            const float4 wv = *(const float4*)&Ws[kk][nt * 4];
            acc[0][0] += av.x * wv.x; acc[0][1] += av.x * wv.y; acc[0][2] += av.x * wv.z; acc[0][3] += av.x * wv.w;
            acc[1][0] += av.y * wv.x; acc[1][1] += av.y * wv.y; acc[1][2] += av.y * wv.z; acc[1][3] += av.y * wv.w;
            acc[2][0] += av.z * wv.x; acc[2][1] += av.z * wv.y; acc[2][2] += av.z * wv.z; acc[2][3] += av.z * wv.w;
            acc[3][0] += av.w * wv.x; acc[3][1] += av.w * wv.y; acc[3][2] += av.w * wv.z; acc[3][3] += av.w * wv.w;
        }
        __syncthreads();
    }

    if (mode == 0) {
#pragma unroll
        for (int r = 0; r < 4; ++r) {
            u32 p0 = (u32)f2bf(acc[r][0]) | ((u32)f2bf(acc[r][1]) << 16);
            u32 p1 = (u32)f2bf(acc[r][2]) | ((u32)f2bf(acc[r][3]) << 16);
            *(uint2*)&C[(size_t)(m0 + mt * 4 + r) * N + n0 + nt * 4] = make_uint2(p0, p1);
        }
    } else {
#pragma unroll
        for (int r = 0; r < 4; ++r)
#pragma unroll
            for (int c = 0; c < 4; ++c)
                Ct[nt * 4 + c][mt * 4 + r] = f2bf(acc[r][c]);
        __syncthreads();
        int r2 = tid >> 2, g = tid & 3;
        int b = m0 >> 9, j0 = m0 & 511;
        u16* cp = C + ((size_t)b * N + n0 + r2) * 512 + j0 + g * 16;
        *(uint4*)cp       = *(const uint4*)&Ct[r2][g * 16];
        *(uint4*)(cp + 8) = *(const uint4*)&Ct[r2][g * 16 + 8];
    }
}

// ---------------------------------------------------------------------------
// Fused attention: one block per (b, i).  j in 8 tiles of 64 with
// unnormalized-softmax accumulation (logits are O(0.1): no running max).
// ---------------------------------------------------------------------------
__global__ __launch_bounds__(256) void attn_kernel(
    const u16* __restrict__ qk,      // [2048][1024] ws bf16
    const u16* __restrict__ cqkt,    // [16][1024][512] ws bf16
    const u16* __restrict__ cv,      // [8192][1024] ws bf16
    const float* __restrict__ bde,   // [16][512][128][32] fp32 input
    const float* __restrict__ bdis,  // [16][512][128][3] fp32 input
    const float* __restrict__ W1,    // [64][128]
    const float* __restrict__ W2,    // [128][64]
    const float* __restrict__ b2,    // [64]
    const float* __restrict__ Wo,    // [1024][256]
    const float* __restrict__ bo,    // [256]
    const float* __restrict__ Wd1,   // [32][64]
    const float* __restrict__ bd1,   // [64]
    const float* __restrict__ Wd2,   // [64][32]
    const float* __restrict__ bd2,   // [32]
    float* __restrict__ out0,        // [2048][256]
    float* __restrict__ out1)        // [2048][96]
{
    __shared__ __align__(16) char smem[63488];
    float* q_lds   = (float*)smem;              // 4096 B : qk row fp32
    u16*   S_lds   = (u16*)(smem + 4096);       // 8704 B : [64][68] s-channels / E
    u16*   T_lds   = (u16*)(smem + 12800);      // 17408 B: [128][68] mish(t1)
    u16*   W1_lds  = (u16*)(smem + 30208);      // 16384 B
    u16*   W2_lds  = (u16*)(smem + 46592);      // 16384 B
    float* denomv  = (float*)(smem + 62976);    // 256 B
    float* fb2     = (float*)(smem + 63232);    // 256 B
    // epilogue overlays (T region, dead after the j loop):
    float* pre   = (float*)(smem + 12800);          // 1024 f
    float* odisv = (float*)(smem + 12800 + 4096);   // 96 f
    float* r1v   = (float*)(smem + 12800 + 4480);   // 192 f

    const int tid = threadIdx.x;
    const int blk = blockIdx.x;
    const int b = blk >> 7;        // batch
    const int i = blk & 127;       // ligand index
    const int row = blk;           // b*128+i

    const float SCALE = 0.17677669529663687f;   // 32^-0.5

    for (int k = tid; k < 1024; k += 256) q_lds[k] = bf2f(qk[(size_t)row * 1024 + k]);
    for (int k = tid; k < 64 * 128; k += 256) W1_lds[k] = f2bf(W1[k]);
    for (int k = tid; k < 128 * 64; k += 256) W2_lds[k] = f2bf(W2[k]);
    if (tid < 64) { denomv[tid] = 0.f; fb2[tid] = b2[tid]; }

    float acc_out[4] = {0.f, 0.f, 0.f, 0.f};   // hd = tid*4 .. +3
    float acc_dis = 0.f;                       // tid<96: (d=tid>>5, hh=tid&31)
    __syncthreads();

    for (int jt = 0; jt < 8; ++jt) {
        const int j0 = jt * 64;

        // ---- phase 1: sim + dis channels -> S_lds[e][j] ----
        {
            const int j = tid & 63;
            const int hq = tid >> 6;           // 0..3, 8 heads each
#pragma unroll
            for (int hh = 0; hh < 8; ++hh) {
                const int h = hq * 8 + hh;
                const u16* cp = cqkt + ((size_t)b * 1024 + h * 32) * 512 + j0 + j;
                float s = 0.f;
#pragma unroll
                for (int d = 0; d < 32; ++d)
                    s += q_lds[h * 32 + d] * bf2f(cp[(size_t)d * 512]);
                S_lds[h * 68 + j] = f2bf(s * SCALE);
            }
            const float* dp = bde + (((size_t)(b * 512 + j0 + j) * 128) + i) * 32 + hq * 8;
            const float4 d0 = *(const float4*)dp;
            const float4 d1 = *(const float4*)(dp + 4);
            const int eb = 32 + hq * 8;
            S_lds[(eb + 0) * 68 + j] = f2bf(d0.x);
            S_lds[(eb + 1) * 68 + j] = f2bf(d0.y);
            S_lds[(eb + 2) * 68 + j] = f2bf(d0.z);
            S_lds[(eb + 3) * 68 + j] = f2bf(d0.w);
            S_lds[(eb + 4) * 68 + j] = f2bf(d1.x);
            S_lds[(eb + 5) * 68 + j] = f2bf(d1.y);
            S_lds[(eb + 6) * 68 + j] = f2bf(d1.z);
            S_lds[(eb + 7) * 68 + j] = f2bf(d1.w);
        }
        __syncthreads();

        // ---- phase 2: MLP1 t1[j][c] = S @ W1, tile 4j x 8c, mish -> T ----
        {
            const int jt4 = (tid & 15) * 4;
            const int c8  = (tid >> 4) * 8;
            float acc[4][8] = {};
#pragma unroll
            for (int e = 0; e < 64; ++e) {
                const uint2 ua = *(const uint2*)&S_lds[e * 68 + jt4];
                const uint4 uw = *(const uint4*)&W1_lds[e * 128 + c8];
                float a0 = bflo(ua.x), a1 = bfhi(ua.x), a2 = bflo(ua.y), a3 = bfhi(ua.y);
                float w0 = bflo(uw.x), w1 = bfhi(uw.x), w2 = bflo(uw.y), w3 = bfhi(uw.y);
                float w4 = bflo(uw.z), w5 = bfhi(uw.z), w6 = bflo(uw.w), w7 = bfhi(uw.w);
#define FMA8(jj, av) { acc[jj][0]+=av*w0; acc[jj][1]+=av*w1; acc[jj][2]+=av*w2; acc[jj][3]+=av*w3; \
                       acc[jj][4]+=av*w4; acc[jj][5]+=av*w5; acc[jj][6]+=av*w6; acc[jj][7]+=av*w7; }
                FMA8(0, a0) FMA8(1, a1) FMA8(2, a2) FMA8(3, a3)
#undef FMA8
            }
#pragma unroll
            for (int cc = 0; cc < 8; ++cc)
#pragma unroll
                for (int jj = 0; jj < 4; ++jj)
                    T_lds[(c8 + cc) * 68 + jt4 + jj] = f2bf(mishf(acc[jj][cc]));
        }
        __syncthreads();

        // ---- phase 3: MLP2 u[j][o] = T @ W2 + b2, exp -> E (S region) ----
        {
            const int jt4 = (tid & 15) * 4;
            const int o4  = (tid >> 4) * 4;
            float acc[4][4] = {};
#pragma unroll
            for (int c = 0; c < 128; ++c) {
                const uint2 ua = *(const uint2*)&T_lds[c * 68 + jt4];
                const uint2 uw = *(const uint2*)&W2_lds[c * 64 + o4];
                float a0 = bflo(ua.x), a1 = bfhi(ua.x), a2 = bflo(ua.y), a3 = bfhi(ua.y);
                float w0 = bflo(uw.x), w1 = bfhi(uw.x), w2 = bflo(uw.y), w3 = bfhi(uw.y);
                acc[0][0] += a0 * w0; acc[0][1] += a0 * w1; acc[0][2] += a0 * w2; acc[0][3] += a0 * w3;
                acc[1][0] += a1 * w0; acc[1][1] += a1 * w1; acc[1][2] += a1 * w2; acc[1][3] += a1 * w3;
                acc[2][0] += a2 * w0; acc[2][1] += a2 * w1; acc[2][2] += a2 * w2; acc[2][3] += a2 * w3;
                acc[3][0] += a3 * w0; acc[3][1] += a3 * w1; acc[3][2] += a3 * w2; acc[3][3] += a3 * w3;
            }
#pragma unroll
            for (int oo = 0; oo < 4; ++oo)
#pragma unroll
                for (int jj = 0; jj < 4; ++jj)
                    S_lds[(o4 + oo) * 68 + jt4 + jj] =
                        f2bf(__expf(acc[jj][oo] + fb2[o4 + oo]));
        }
        __syncthreads();

        // ---- phase 4: accumulate denom, out, out_dis ----
        {
            const int h = tid >> 3;            // head of hd = tid*4
            const u16* cvp = cv + (size_t)(b * 512 + j0) * 1024 + tid * 4;
#pragma unroll 8
            for (int j = 0; j < 64; ++j) {
                float e = bf2f(S_lds[h * 68 + j]);
                const uint2 v = *(const uint2*)(cvp + (size_t)j * 1024);
                acc_out[0] += e * bflo(v.x); acc_out[1] += e * bfhi(v.x);
                acc_out[2] += e * bflo(v.y); acc_out[3] += e * bfhi(v.y);
            }
            if (tid < 64) {
                float s = 0.f;
#pragma unroll 8
                for (int j = 0; j < 64; ++j) s += bf2f(S_lds[tid * 68 + j]);
                denomv[tid] += s;
            }
            if (tid < 96) {
                const int d = tid >> 5, hh = tid & 31;
                const float* bp = bdis + ((size_t)(b * 512 + j0) * 128 + i) * 3 + d;
                float s = 0.f;
#pragma unroll 8
                for (int j = 0; j < 64; ++j)
                    s += bf2f(S_lds[(32 + hh) * 68 + j]) * bp[(size_t)j * 384];
                acc_dis += s;
            }
        }
        __syncthreads();
    }

    // ---- epilogue: normalize, W_o, dis-MLP ----
    {
        const float dn = denomv[tid >> 3];
        pre[tid * 4 + 0] = acc_out[0] / dn;
        pre[tid * 4 + 1] = acc_out[1] / dn;
        pre[tid * 4 + 2] = acc_out[2] / dn;
        pre[tid * 4 + 3] = acc_out[3] / dn;
        if (tid < 96) odisv[tid] = acc_dis / denomv[32 + (tid & 31)];
    }
    __syncthreads();
    {   // out0[row][col] = pre . Wo[:,col] + bo[col]
        const int col = tid;   // 0..255
        float o = bo[col];
#pragma unroll 8
        for (int k = 0; k < 1024; ++k)
            o += pre[k] * Wo[(size_t)k * 256 + col];
        out0[(size_t)row * 256 + col] = o;
        // dis-MLP layer 1: r1[d][c] = mish(odis[d,:] . Wd1[:,c] + bd1[c])
        if (tid < 192) {
            const int d = tid >> 6, c = tid & 63;
            float t = bd1[c];
#pragma unroll
            for (int hh = 0; hh < 32; ++hh)
                t += odisv[d * 32 + hh] * Wd1[hh * 64 + c];
            r1v[d * 64 + c] = mishf(t);
        }
    }
    __syncthreads();
    if (tid < 96) {   // layer 2
        const int d = tid >> 5, hh = tid & 31;
        float v = bd2[hh];
#pragma unroll
        for (int c = 0; c < 64; ++c)
            v += r1v[d * 64 + c] * Wd2[c * 32 + hh];
        out1[(size_t)row * 96 + d * 32 + hh] = v;
    }
}

extern "C" void kernel_launch(void* const* d_in, const int* in_sizes, int n_in,
                              void* d_out, int out_size, void* d_ws, size_t ws_size,
                              hipStream_t stream) {
    const float* x    = (const float*)d_in[0];
    const float* ctx  = (const float*)d_in[1];
    const float* bdis = (const float*)d_in[2];
    const float* bde  = (const float*)d_in[3];
    // d_in[4] protein_len, d_in[5] ligand_len: fixed 512/128. d_in[7] W_v unused.
    const float* Wqk  = (const float*)d_in[6];
    const float* Wcqk = (const float*)d_in[8];
    const float* Wcv  = (const float*)d_in[9];
    const float* Wm1  = (const float*)d_in[10];
    const float* Wm2  = (const float*)d_in[11];
    const float* bm2  = (const float*)d_in[12];
    const float* Wo   = (const float*)d_in[13];
    const float* bo   = (const float*)d_in[14];
    const float* Wd1  = (const float*)d_in[15];
    const float* bd1  = (const float*)d_in[16];
    const float* Wd2  = (const float*)d_in[17];
    const float* bd2  = (const float*)d_in[18];

    u16* qk_ws   = (u16*)d_ws;                          // 2048*1024
    u16* cqkt_ws = qk_ws + (size_t)2048 * 1024;         // 16*1024*512
    u16* cv_ws   = cqkt_ws + (size_t)16 * 1024 * 512;   // 8192*1024
    float* out0 = (float*)d_out;
    float* out1 = out0 + (size_t)2048 * 256;

    gemm_f32<<<dim3(16, 32),  256, 0, stream>>>(x,   Wqk,  qk_ws,   2048, 1024, 256, 0);
    gemm_f32<<<dim3(16, 128), 256, 0, stream>>>(ctx, Wcqk, cqkt_ws, 8192, 1024, 256, 1);
    gemm_f32<<<dim3(16, 128), 256, 0, stream>>>(ctx, Wcv,  cv_ws,   8192, 1024, 256, 0);
    attn_kernel<<<2048, 256, 0, stream>>>(qk_ws, cqkt_ws, cv_ws, bde, bdis,
                                          Wm1, Wm2, bm2, Wo, bo, Wd1, bd1, Wd2, bd2,
                                          out0, out1);
}

// Round 3
// 866.080 us; speedup vs baseline: 4.8178x; 4.8178x over previous
//
#include <hip/hip_runtime.h>

typedef unsigned short u16;
typedef unsigned int   u32;
typedef __attribute__((ext_vector_type(8))) short bf16x8;
typedef __attribute__((ext_vector_type(4))) float f32x4;

#define MFMA_BF16 __builtin_amdgcn_mfma_f32_16x16x32_bf16

__device__ __forceinline__ float bf2f(u16 v) {
    u32 x = ((u32)v) << 16;
    return __builtin_bit_cast(float, x);
}
__device__ __forceinline__ float bflo(u32 u) { return __builtin_bit_cast(float, u << 16); }
__device__ __forceinline__ float bfhi(u32 u) { return __builtin_bit_cast(float, u & 0xffff0000u); }
__device__ __forceinline__ u16 f2bf(float f) {
    u32 x = __builtin_bit_cast(u32, f);
    u32 r = (x + 0x7fffu + ((x >> 16) & 1u)) >> 16;
    return (u16)r;
}
__device__ __forceinline__ float mishf(float x) {
    float p = 1.f + __expf(x);
    float q = p * p;
    float r = (q - 1.f) / (q + 1.f);
    return (x > 20.f) ? x : x * r;
}

// ---------------------------------------------------------------------------
// fp32-in GEMM (scalar VALU, from round 2): C[M,N] = A[M,K] @ W[K,N] * scale.
// mode 0: row-major bf16 store. mode 1: per-batch transposed C_t[b][n][m%512].
// ---------------------------------------------------------------------------
__global__ __launch_bounds__(256) void gemm_f32(
    const float* __restrict__ A, const float* __restrict__ W, u16* __restrict__ C,
    int M, int N, int K, int mode, float scale)
{
    __shared__ float As[32][68];
    __shared__ float Ws[32][64];
    __shared__ u16 Ct[64][72];

    const int tid = threadIdx.x;
    const int m0 = blockIdx.y * 64, n0 = blockIdx.x * 64;
    const int mt = tid >> 4, nt = tid & 15;

    float acc[4][4] = {};

    for (int k0 = 0; k0 < K; k0 += 32) {
        {
            int r = tid >> 2, q = tid & 3;
            const float* ap = A + (size_t)(m0 + r) * K + k0 + q * 8;
            const float4 a0 = *(const float4*)ap;
            const float4 a1 = *(const float4*)(ap + 4);
            As[q * 8 + 0][r] = a0.x; As[q * 8 + 1][r] = a0.y;
            As[q * 8 + 2][r] = a0.z; As[q * 8 + 3][r] = a0.w;
            As[q * 8 + 4][r] = a1.x; As[q * 8 + 5][r] = a1.y;
            As[q * 8 + 6][r] = a1.z; As[q * 8 + 7][r] = a1.w;
        }
        {
            int kr = tid >> 3, g = tid & 7;
            const float* wp = W + (size_t)(k0 + kr) * N + n0 + g * 8;
            *(float4*)&Ws[kr][g * 8]     = *(const float4*)wp;
            *(float4*)&Ws[kr][g * 8 + 4] = *(const float4*)(wp + 4);
        }
        __syncthreads();
#pragma unroll
        for (int kk = 0; kk < 32; ++kk) {
            const float4 av = *(const float4*)&As[kk][mt * 4];
            const float4 wv = *(const float4*)&Ws[kk][nt * 4];
            acc[0][0] += av.x * wv.x; acc[0][1] += av.x * wv.y; acc[0][2] += av.x * wv.z; acc[0][3] += av.x * wv.w;
            acc[1][0] += av.y * wv.x; acc[1][1] += av.y * wv.y; acc[1][2] += av.y * wv.z; acc[1][3] += av.y * wv.w;
            acc[2][0] += av.z * wv.x; acc[2][1] += av.z * wv.y; acc[2][2] += av.z * wv.z; acc[2][3] += av.z * wv.w;
            acc[3][0] += av.w * wv.x; acc[3][1] += av.w * wv.y; acc[3][2] += av.w * wv.z; acc[3][3] += av.w * wv.w;
        }
        __syncthreads();
    }

    if (mode == 0) {
#pragma unroll
        for (int r = 0; r < 4; ++r) {
            u32 p0 = (u32)f2bf(acc[r][0] * scale) | ((u32)f2bf(acc[r][1] * scale) << 16);
            u32 p1 = (u32)f2bf(acc[r][2] * scale) | ((u32)f2bf(acc[r][3] * scale) << 16);
            *(uint2*)&C[(size_t)(m0 + mt * 4 + r) * N + n0 + nt * 4] = make_uint2(p0, p1);
        }
    } else {
#pragma unroll
        for (int r = 0; r < 4; ++r)
#pragma unroll
            for (int c = 0; c < 4; ++c)
                Ct[nt * 4 + c][mt * 4 + r] = f2bf(acc[r][c] * scale);
        __syncthreads();
        int r2 = tid >> 2, g = tid & 3;
        int b = m0 >> 9, j0 = m0 & 511;
        u16* cp = C + ((size_t)b * N + n0 + r2) * 512 + j0 + g * 16;
        *(uint4*)cp       = *(const uint4*)&Ct[r2][g * 16];
        *(uint4*)(cp + 8) = *(const uint4*)&Ct[r2][g * 16 + 8];
    }
}

// ---------------------------------------------------------------------------
// Prep: WoT[col][k] bf16; W1/W2 swizzled to MFMA B-frag order.
// frag layout: [frag][lane][8 u16], element = W[k = ks*32 + q*8 + j][n0 + n]
// ---------------------------------------------------------------------------
__global__ __launch_bounds__(256) void prep(
    const float* __restrict__ Wo, const float* __restrict__ W1, const float* __restrict__ W2,
    u16* __restrict__ WoT, u16* __restrict__ w1b, u16* __restrict__ w2b)
{
    const int bb = blockIdx.x, t = threadIdx.x;
    if (bb < 256) {
#pragma unroll
        for (int kk = 0; kk < 4; ++kk)
            WoT[(size_t)t * 1024 + bb * 4 + kk] = f2bf(Wo[(size_t)(bb * 4 + kk) * 256 + t]);
    } else {
        for (int u = 0; u < 32; ++u) {        // W1: 8192 el, frag f = ks*8+nt
            int idx = t + 256 * u;
            int j = idx & 7, lane = (idx >> 3) & 63, f = idx >> 9;
            int n = lane & 15, q = lane >> 4, ntc = f & 7, ks = f >> 3;
            w1b[idx] = f2bf(W1[(ks * 32 + q * 8 + j) * 128 + ntc * 16 + n]);
        }
        for (int u = 0; u < 32; ++u) {        // W2: 8192 el, frag f = ks*4+ot
            int idx = t + 256 * u;
            int j = idx & 7, lane = (idx >> 3) & 63, f = idx >> 9;
            int n = lane & 15, q = lane >> 4, ot = f & 3, ks = f >> 2;
            w2b[idx] = f2bf(W2[(ks * 32 + q * 8 + j) * 64 + ot * 16 + n]);
        }
    }
}

// ---------------------------------------------------------------------------
// attn2: block = (b, i-tile 16, j-half 256). 16 passes of 16 j.
// ES rows r = i*16 + jj, 64 channels (stride 72 u16). MFMA everywhere.
// Partial layout per (b,it,jh): [out 16x1024][denom 16x64][dis 16x96] fp32.
// ---------------------------------------------------------------------------
__global__ __launch_bounds__(256, 2) void attn2(
    const u16* __restrict__ qk,      // [2048][1024] bf16
    const u16* __restrict__ cqk,     // [8192][1024] bf16
    const u16* __restrict__ cvT,     // [16][1024][512] bf16
    const float* __restrict__ bde,   // [16][512][128][32]
    const float* __restrict__ bdis,  // [16][512][128][3]
    const u16* __restrict__ w1b, const u16* __restrict__ w2b,
    const float* __restrict__ b2,
    float* __restrict__ partial)
{
    __shared__ u16 ES[256 * 72];
    __shared__ u16 W1B[8192];
    __shared__ u16 miniT[4][16 * 40];
    __shared__ float bdisL[256 * 4];   // [jj*16+i][4]

    const int tid = threadIdx.x;
    const int lane = tid & 63, wv = tid >> 6;
    const int qd = lane >> 4, ln = lane & 15;
    const int blk = blockIdx.x;
    const int jh = blk & 1, it = (blk >> 1) & 7, b = blk >> 4;
    const int i0 = it * 16;
    const int t_i = tid & 15, t_g = tid >> 4;

    for (int k = tid; k < 4096; k += 256) ((u32*)W1B)[k] = ((const u32*)w1b)[k];

    bf16x8 qkf[8];
#pragma unroll
    for (int hh = 0; hh < 8; ++hh) {
        int h = wv * 8 + hh;
        qkf[hh] = *(const bf16x8*)(qk + ((size_t)(b * 128 + i0 + ln)) * 1024 + h * 32 + qd * 8);
    }
    float b2r[4];
#pragma unroll
    for (int ot = 0; ot < 4; ++ot) b2r[ot] = b2[ot * 16 + ln];

    f32x4 oacc[8][2];
#pragma unroll
    for (int a = 0; a < 8; ++a)
#pragma unroll
        for (int c = 0; c < 2; ++c) oacc[a][c] = (f32x4){0.f, 0.f, 0.f, 0.f};
    float dnacc[4] = {0.f, 0.f, 0.f, 0.f};
    float disacc[3][2] = {};

    __syncthreads();

#pragma clang loop unroll(disable)
    for (int ps = 0; ps < 16; ++ps) {
        const int jg0 = jh * 256 + ps * 16;

        // ---- P1: sim (MFMA) + bde channels + bdis stage ----
#pragma unroll
        for (int hh = 0; hh < 8; ++hh) {
            int h = wv * 8 + hh;
            bf16x8 bfv = *(const bf16x8*)(cqk + ((size_t)(b * 512 + jg0 + ln)) * 1024 + h * 32 + qd * 8);
            f32x4 c = (f32x4){0.f, 0.f, 0.f, 0.f};
            c = MFMA_BF16(qkf[hh], bfv, c, 0, 0, 0);
#pragma unroll
            for (int r = 0; r < 4; ++r)
                ES[((qd * 4 + r) * 16 + ln) * 72 + h] = f2bf(c[r]);
        }
        {
            int ii = tid >> 4, jj = tid & 15;
            const float* dp = bde + (((size_t)(b * 512 + jg0 + jj)) * 128 + i0 + ii) * 32;
            u16* er = ES + (ii * 16 + jj) * 72 + 32;
#pragma unroll
            for (int g = 0; g < 4; ++g) {
                float4 a = ((const float4*)dp)[2 * g];
                float4 bq = ((const float4*)dp)[2 * g + 1];
                bf16x8 v;
                v[0] = (short)f2bf(a.x);  v[1] = (short)f2bf(a.y);
                v[2] = (short)f2bf(a.z);  v[3] = (short)f2bf(a.w);
                v[4] = (short)f2bf(bq.x); v[5] = (short)f2bf(bq.y);
                v[6] = (short)f2bf(bq.z); v[7] = (short)f2bf(bq.w);
                *(bf16x8*)(void*)(er + g * 8) = v;
            }
        }
        {
            int jj = tid >> 4, ii = tid & 15;
            const float* sp = bdis + (((size_t)(b * 512 + jg0 + jj)) * 128 + i0 + ii) * 3;
            float* d = bdisL + (jj * 16 + ii) * 4;
            d[0] = sp[0]; d[1] = sp[1]; d[2] = sp[2];
        }
        __syncthreads();

        // ---- P2: MLP1 -> mish -> miniT -> MLP2 -> exp (in place) ----
#pragma clang loop unroll(disable)
        for (int s = 0; s < 4; ++s) {
            const int r0 = wv * 64 + s * 16;
            bf16x8 af0 = *(const bf16x8*)&ES[(r0 + ln) * 72 + qd * 8];
            bf16x8 af1 = *(const bf16x8*)&ES[(r0 + ln) * 72 + 32 + qd * 8];
            f32x4 uacc[4];
#pragma unroll
            for (int ot = 0; ot < 4; ++ot) uacc[ot] = (f32x4){0.f, 0.f, 0.f, 0.f};
            u16* mt = &miniT[wv][0];
#pragma unroll
            for (int cg = 0; cg < 4; ++cg) {
                bf16x8 w00 = *(const bf16x8*)&W1B[((cg * 2 + 0) * 64 + lane) * 8];
                bf16x8 w01 = *(const bf16x8*)&W1B[((cg * 2 + 1) * 64 + lane) * 8];
                bf16x8 w10 = *(const bf16x8*)&W1B[((8 + cg * 2 + 0) * 64 + lane) * 8];
                bf16x8 w11 = *(const bf16x8*)&W1B[((8 + cg * 2 + 1) * 64 + lane) * 8];
                f32x4 t0 = (f32x4){0.f, 0.f, 0.f, 0.f}, t1 = t0;
                t0 = MFMA_BF16(af0, w00, t0, 0, 0, 0);
                t0 = MFMA_BF16(af1, w10, t0, 0, 0, 0);
                t1 = MFMA_BF16(af0, w01, t1, 0, 0, 0);
                t1 = MFMA_BF16(af1, w11, t1, 0, 0, 0);
#pragma unroll
                for (int r = 0; r < 4; ++r) {
                    mt[(qd * 4 + r) * 40 + ln]      = f2bf(mishf(t0[r]));
                    mt[(qd * 4 + r) * 40 + 16 + ln] = f2bf(mishf(t1[r]));
                }
                bf16x8 ta = *(const bf16x8*)&mt[ln * 40 + qd * 8];
#pragma unroll
                for (int ot = 0; ot < 4; ++ot) {
                    bf16x8 wf = *(const bf16x8*)(w2b + ((size_t)(cg * 4 + ot) * 64 + lane) * 8);
                    uacc[ot] = MFMA_BF16(ta, wf, uacc[ot], 0, 0, 0);
                }
            }
#pragma unroll
            for (int ot = 0; ot < 4; ++ot)
#pragma unroll
                for (int r = 0; r < 4; ++r)
                    ES[(r0 + qd * 4 + r) * 72 + ot * 16 + ln] = f2bf(__expf(uacc[ot][r] + b2r[ot]));
        }
        __syncthreads();

        // ---- P3: attn@cv (MFMA, K zero-padded), denom, dis ----
#pragma unroll
        for (int hh = 0; hh < 8; ++hh) {
            int h = wv * 8 + hh;
            bf16x8 ef = (bf16x8){0, 0, 0, 0, 0, 0, 0, 0};
            if (qd < 2) {
#pragma unroll
                for (int j = 0; j < 8; ++j)
                    ef[j] = (short)ES[(ln * 16 + qd * 8 + j) * 72 + h];
            }
#pragma unroll
            for (int nt = 0; nt < 2; ++nt) {
                bf16x8 cf = (bf16x8){0, 0, 0, 0, 0, 0, 0, 0};
                if (qd < 2)
                    cf = *(const bf16x8*)(cvT + ((size_t)(b * 1024 + h * 32 + nt * 16 + ln)) * 512 + jg0 + qd * 8);
                oacc[hh][nt] = MFMA_BF16(ef, cf, oacc[hh][nt], 0, 0, 0);
            }
        }
#pragma unroll
        for (int jj = 0; jj < 16; ++jj) {
            const u16* ep = &ES[(t_i * 16 + jj) * 72 + t_g * 4];
            u32 lo = *(const u32*)ep, hi = *(const u32*)(ep + 2);
            dnacc[0] += bflo(lo); dnacc[1] += bfhi(lo);
            dnacc[2] += bflo(hi); dnacc[3] += bfhi(hi);
        }
        {
            const int hc = 32 + t_g * 2;
#pragma unroll
            for (int jj = 0; jj < 16; ++jj) {
                u32 ee = *(const u32*)&ES[(t_i * 16 + jj) * 72 + hc];
                float e0 = bflo(ee), e1 = bfhi(ee);
                const float4 dv = *(const float4*)&bdisL[(jj * 16 + t_i) * 4];
                disacc[0][0] += e0 * dv.x; disacc[0][1] += e1 * dv.x;
                disacc[1][0] += e0 * dv.y; disacc[1][1] += e1 * dv.y;
                disacc[2][0] += e0 * dv.z; disacc[2][1] += e1 * dv.z;
            }
        }
        __syncthreads();
    }

    float* P = partial + (size_t)((b * 8 + it) * 2 + jh) * 18944;
#pragma unroll
    for (int hh = 0; hh < 8; ++hh)
#pragma unroll
        for (int nt = 0; nt < 2; ++nt)
#pragma unroll
            for (int r = 0; r < 4; ++r)
                P[(size_t)(qd * 4 + r) * 1024 + (wv * 8 + hh) * 32 + nt * 16 + ln] = oacc[hh][nt][r];
#pragma unroll
    for (int k = 0; k < 4; ++k) P[16384 + t_i * 64 + t_g * 4 + k] = dnacc[k];
#pragma unroll
    for (int d = 0; d < 3; ++d) {
        P[17408 + t_i * 96 + d * 32 + t_g * 2]     = disacc[d][0];
        P[17408 + t_i * 96 + d * 32 + t_g * 2 + 1] = disacc[d][1];
    }
}

// ---------------------------------------------------------------------------
// finalize: per (b,it): combine jh partials, normalize, Wo epilogue (MFMA),
// dis-MLP. 128 blocks x 256 threads.
// ---------------------------------------------------------------------------
__global__ __launch_bounds__(256, 2) void finalize(
    const float* __restrict__ partial, const u16* __restrict__ WoT,
    const float* __restrict__ bo,
    const float* __restrict__ Wd1, const float* __restrict__ bd1,
    const float* __restrict__ Wd2, const float* __restrict__ bd2,
    float* __restrict__ out0, float* __restrict__ out1)
{
    __shared__ float denomL[1024];
    __shared__ u16 preL[16 * 1032];
    __shared__ float odisL[1536];
    __shared__ float r1L[3072];

    const int tid = threadIdx.x;
    const int f = blockIdx.x;
    const int b = f >> 3, it = f & 7;
    const int row0 = b * 128 + it * 16;
    const float* P0 = partial + (size_t)f * 2 * 18944;
    const float* P1 = P0 + 18944;

    for (int k = tid; k < 1024; k += 256) denomL[k] = P0[16384 + k] + P1[16384 + k];
    __syncthreads();

    {
        const int h = (tid * 4) >> 5;
#pragma unroll
        for (int i = 0; i < 16; ++i) {
            float4 a = *(const float4*)&P0[(size_t)i * 1024 + tid * 4];
            float4 bq = *(const float4*)&P1[(size_t)i * 1024 + tid * 4];
            float rdn = 1.f / denomL[i * 64 + h];
            u32 p0 = (u32)f2bf((a.x + bq.x) * rdn) | ((u32)f2bf((a.y + bq.y) * rdn) << 16);
            u32 p1 = (u32)f2bf((a.z + bq.z) * rdn) | ((u32)f2bf((a.w + bq.w) * rdn) << 16);
            *(uint2*)(void*)&preL[i * 1032 + tid * 4] = make_uint2(p0, p1);
        }
    }
    for (int idx = tid; idx < 1536; idx += 256) {
        int i = idx / 96, rm = idx % 96, h = rm & 31;
        odisL[idx] = (P0[17408 + idx] + P1[17408 + idx]) / denomL[i * 64 + 32 + h];
    }
    __syncthreads();

    {
        const int lane = tid & 63, wv = tid >> 6;
        const int qd = lane >> 4, ln = lane & 15;
        f32x4 acc[4];
#pragma unroll
        for (int nt = 0; nt < 4; ++nt) acc[nt] = (f32x4){0.f, 0.f, 0.f, 0.f};
#pragma clang loop unroll(disable)
        for (int ks = 0; ks < 32; ++ks) {
            bf16x8 af = *(const bf16x8*)&preL[ln * 1032 + ks * 32 + qd * 8];
#pragma unroll
            for (int nt = 0; nt < 4; ++nt) {
                bf16x8 wf = *(const bf16x8*)(WoT + ((size_t)(wv * 64 + nt * 16 + ln)) * 1024 + ks * 32 + qd * 8);
                acc[nt] = MFMA_BF16(af, wf, acc[nt], 0, 0, 0);
            }
        }
#pragma unroll
        for (int nt = 0; nt < 4; ++nt) {
            int col = wv * 64 + nt * 16 + ln;
            float bv = bo[col];
#pragma unroll
            for (int r = 0; r < 4; ++r)
                out0[(size_t)(row0 + qd * 4 + r) * 256 + col] = acc[nt][r] + bv;
        }
    }

    for (int idx = tid; idx < 3072; idx += 256) {
        int i = idx / 192, rm = idx % 192, d = rm / 64, c = rm & 63;
        float t = bd1[c];
#pragma unroll
        for (int hh = 0; hh < 32; ++hh)
            t += odisL[i * 96 + d * 32 + hh] * Wd1[hh * 64 + c];
        r1L[idx] = mishf(t);
    }
    __syncthreads();
    for (int idx = tid; idx < 1536; idx += 256) {
        int i = idx / 96, rm = idx % 96, d = rm >> 5, h = rm & 31;
        float v = bd2[h];
#pragma unroll
        for (int c = 0; c < 64; ++c)
            v += r1L[i * 192 + d * 64 + c] * Wd2[c * 32 + h];
        out1[(size_t)(row0 + i) * 96 + d * 32 + h] = v;
    }
}

extern "C" void kernel_launch(void* const* d_in, const int* in_sizes, int n_in,
                              void* d_out, int out_size, void* d_ws, size_t ws_size,
                              hipStream_t stream) {
    const float* x    = (const float*)d_in[0];
    const float* ctx  = (const float*)d_in[1];
    const float* bdis = (const float*)d_in[2];
    const float* bde  = (const float*)d_in[3];
    const float* Wqk  = (const float*)d_in[6];
    const float* Wcqk = (const float*)d_in[8];
    const float* Wcv  = (const float*)d_in[9];
    const float* Wm1  = (const float*)d_in[10];
    const float* Wm2  = (const float*)d_in[11];
    const float* bm2  = (const float*)d_in[12];
    const float* Wo   = (const float*)d_in[13];
    const float* bo   = (const float*)d_in[14];
    const float* Wd1  = (const float*)d_in[15];
    const float* bd1  = (const float*)d_in[16];
    const float* Wd2  = (const float*)d_in[17];
    const float* bd2  = (const float*)d_in[18];

    char* ws = (char*)d_ws;
    u16* qk_ws  = (u16*)(ws);                       // 4 MB
    u16* cqk_ws = (u16*)(ws + 4194304);             // 16 MB
    u16* cvT_ws = (u16*)(ws + 20971520);            // 16 MB
    u16* w1b    = (u16*)(ws + 37748736);            // 16 KB
    u16* w2b    = (u16*)(ws + 37765120);            // 16 KB
    u16* WoT    = (u16*)(ws + 37781504);            // 512 KB
    float* part = (float*)(ws + 38305792);          // 18.5 MB

    float* out0 = (float*)d_out;
    float* out1 = out0 + (size_t)2048 * 256;

    const float SCALE = 0.17677669529663687f;       // 32^-0.5, folded into qk

    prep<<<257, 256, 0, stream>>>(Wo, Wm1, Wm2, WoT, w1b, w2b);
    gemm_f32<<<dim3(16, 32),  256, 0, stream>>>(x,   Wqk,  qk_ws,  2048, 1024, 256, 0, SCALE);
    gemm_f32<<<dim3(16, 128), 256, 0, stream>>>(ctx, Wcqk, cqk_ws, 8192, 1024, 256, 0, 1.0f);
    gemm_f32<<<dim3(16, 128), 256, 0, stream>>>(ctx, Wcv,  cvT_ws, 8192, 1024, 256, 1, 1.0f);
    attn2<<<256, 256, 0, stream>>>(qk_ws, cqk_ws, cvT_ws, bde, bdis, w1b, w2b, bm2, part);
    finalize<<<128, 256, 0, stream>>>(part, WoT, bo, Wd1, bd1, Wd2, bd2, out0, out1);
}

// Round 4
// 629.663 us; speedup vs baseline: 6.6268x; 1.3755x over previous
//
#include <hip/hip_runtime.h>

typedef unsigned short u16;
typedef unsigned int   u32;
typedef __attribute__((ext_vector_type(8))) short bf16x8;
typedef __attribute__((ext_vector_type(4))) float f32x4;

#define MFMA_BF16 __builtin_amdgcn_mfma_f32_16x16x32_bf16

__device__ __forceinline__ float bf2f(u16 v) {
    u32 x = ((u32)v) << 16;
    return __builtin_bit_cast(float, x);
}
__device__ __forceinline__ float bflo(u32 u) { return __builtin_bit_cast(float, u << 16); }
__device__ __forceinline__ float bfhi(u32 u) { return __builtin_bit_cast(float, u & 0xffff0000u); }
__device__ __forceinline__ u16 f2bf(float f) {
    u32 x = __builtin_bit_cast(u32, f);
    u32 r = (x + 0x7fffu + ((x >> 16) & 1u)) >> 16;
    return (u16)r;
}
__device__ __forceinline__ float mishf(float x) {
    float p = 1.f + __expf(x);
    float q = p * p;
    float r = (q - 1.f) / (q + 1.f);
    return (x > 20.f) ? x : x * r;
}

// ---------------------------------------------------------------------------
// MFMA GEMM: C[M,N] = bf16( A[M,K] @ W[K,N] * scale ), fp32 in, bf16 out.
// Tile 128M x 64N, K-step 32, 256 thr. M % 128 == 0, N = 1024, K = 256.
// ---------------------------------------------------------------------------
__global__ __launch_bounds__(256) void gemm_mfma(
    const float* __restrict__ A, const float* __restrict__ W, u16* __restrict__ C,
    int M, int N, int K, float scale)
{
    __shared__ u16 As[128 * 40];     // [row][k], stride 40 u16 (80 B, 16B-aligned)
    __shared__ u16 Bf[4 * 64 * 8];   // B frags: [(nt*64+lane)*8]

    const int tid = threadIdx.x;
    const int lane = tid & 63, wv = tid >> 6;
    const int qd = lane >> 4, ln = lane & 15;
    const int m0 = blockIdx.y * 128, n0 = blockIdx.x * 64;

    f32x4 acc[2][4];
#pragma unroll
    for (int a = 0; a < 2; ++a)
#pragma unroll
        for (int nt = 0; nt < 4; ++nt) acc[a][nt] = (f32x4){0.f, 0.f, 0.f, 0.f};

    for (int k0 = 0; k0 < K; k0 += 32) {
        {   // stage A -> bf16: 2 threads/row, 16 k each
            int r = tid >> 1, kh = (tid & 1) * 16;
            const float* ap = A + (size_t)(m0 + r) * K + k0 + kh;
            float4 a0 = ((const float4*)ap)[0];
            float4 a1 = ((const float4*)ap)[1];
            float4 a2 = ((const float4*)ap)[2];
            float4 a3 = ((const float4*)ap)[3];
            uint4 p0, p1;
            p0.x = (u32)f2bf(a0.x) | ((u32)f2bf(a0.y) << 16);
            p0.y = (u32)f2bf(a0.z) | ((u32)f2bf(a0.w) << 16);
            p0.z = (u32)f2bf(a1.x) | ((u32)f2bf(a1.y) << 16);
            p0.w = (u32)f2bf(a1.z) | ((u32)f2bf(a1.w) << 16);
            p1.x = (u32)f2bf(a2.x) | ((u32)f2bf(a2.y) << 16);
            p1.y = (u32)f2bf(a2.z) | ((u32)f2bf(a2.w) << 16);
            p1.z = (u32)f2bf(a3.x) | ((u32)f2bf(a3.y) << 16);
            p1.w = (u32)f2bf(a3.z) | ((u32)f2bf(a3.w) << 16);
            *(uint4*)&As[r * 40 + kh]     = p0;
            *(uint4*)&As[r * 40 + kh + 8] = p1;
        }
        {   // stage B direct to frag order: thread = (nt, q, nn)
            int nt = tid >> 6, q = (tid >> 4) & 3, nn = tid & 15;
            const float* wp = W + (size_t)(k0 + q * 8) * N + n0 + nt * 16 + nn;
            bf16x8 v;
#pragma unroll
            for (int j = 0; j < 8; ++j) v[j] = (short)f2bf(wp[(size_t)j * N]);
            *(bf16x8*)&Bf[tid * 8] = v;
        }
        __syncthreads();
        bf16x8 af0 = *(const bf16x8*)&As[(wv * 32 + ln) * 40 + qd * 8];
        bf16x8 af1 = *(const bf16x8*)&As[(wv * 32 + 16 + ln) * 40 + qd * 8];
#pragma unroll
        for (int nt = 0; nt < 4; ++nt) {
            bf16x8 bfr = *(const bf16x8*)&Bf[(nt * 64 + lane) * 8];
            acc[0][nt] = MFMA_BF16(af0, bfr, acc[0][nt], 0, 0, 0);
            acc[1][nt] = MFMA_BF16(af1, bfr, acc[1][nt], 0, 0, 0);
        }
        __syncthreads();
    }
#pragma unroll
    for (int a = 0; a < 2; ++a)
#pragma unroll
        for (int nt = 0; nt < 4; ++nt)
#pragma unroll
            for (int r = 0; r < 4; ++r)
                C[(size_t)(m0 + wv * 32 + a * 16 + qd * 4 + r) * N + n0 + nt * 16 + ln] =
                    f2bf(acc[a][nt][r] * scale);
}

// ---------------------------------------------------------------------------
// Prep: WoT[col][k] bf16; W1/W2 swizzled to MFMA B-frag order.
// ---------------------------------------------------------------------------
__global__ __launch_bounds__(256) void prep(
    const float* __restrict__ Wo, const float* __restrict__ W1, const float* __restrict__ W2,
    u16* __restrict__ WoT, u16* __restrict__ w1b, u16* __restrict__ w2b)
{
    const int bb = blockIdx.x, t = threadIdx.x;
    if (bb < 256) {
#pragma unroll
        for (int kk = 0; kk < 4; ++kk)
            WoT[(size_t)t * 1024 + bb * 4 + kk] = f2bf(Wo[(size_t)(bb * 4 + kk) * 256 + t]);
    } else {
        for (int u = 0; u < 32; ++u) {        // W1: frag f = ks*8+nt
            int idx = t + 256 * u;
            int j = idx & 7, lane = (idx >> 3) & 63, f = idx >> 9;
            int n = lane & 15, q = lane >> 4, ntc = f & 7, ks = f >> 3;
            w1b[idx] = f2bf(W1[(ks * 32 + q * 8 + j) * 128 + ntc * 16 + n]);
        }
        for (int u = 0; u < 32; ++u) {        // W2: frag f = ks*4+ot
            int idx = t + 256 * u;
            int j = idx & 7, lane = (idx >> 3) & 63, f = idx >> 9;
            int n = lane & 15, q = lane >> 4, ot = f & 3, ks = f >> 2;
            w2b[idx] = f2bf(W2[(ks * 32 + q * 8 + j) * 64 + ot * 16 + n]);
        }
    }
}

// ---------------------------------------------------------------------------
// attn3: block = (b, i-tile 16, j-quarter 128). 8 passes of 16 j.
// Per pass: P1 sim MFMA -> ES[256 rows][32 ch]; P2 per-s MLP (bde A-frag
// loaded direct from global), E stays in REGISTERS; P3 PV via ds_bpermute +
// VALU against contiguous cv rows. denom/dis reduced by shfl at the end.
// Partial per block: [out 16x1024][denom 16x64][dis 16x96] fp32 (18944 f).
// ---------------------------------------------------------------------------
__global__ __launch_bounds__(256, 2) void attn3(
    const u16* __restrict__ qk,      // [2048][1024] bf16 (scale folded)
    const u16* __restrict__ cqk,     // [8192][1024] bf16
    const u16* __restrict__ cv,      // [8192][1024] bf16 row-major
    const float* __restrict__ bde,   // [16][512][128][32]
    const float* __restrict__ bdis,  // [16][512][128][3]
    const u16* __restrict__ w1b, const u16* __restrict__ w2b,
    const float* __restrict__ b2,
    float* __restrict__ partial)
{
    __shared__ u16 ES[256 * 40];       // [row=(i,j)][32 sim ch], stride 40
    __shared__ u16 W1B[8192];
    __shared__ u16 miniT[4][16 * 40];  // per-wave T tile [16 rows][32 c]
    __shared__ float bdisL[256 * 4];   // [jj*16+ii][4]

    const int tid = threadIdx.x;
    const int lane = tid & 63, wv = tid >> 6;
    const int qd = lane >> 4, ln = lane & 15;
    const int blk = blockIdx.x;
    const int jq = blk & 3, it = (blk >> 2) & 7, b = blk >> 5;
    const int i0 = it * 16;
    const int srcbase = ((lane >> 1) & 15) * 4;   // bpermute byte base
    const u32 sh = (lane & 32) >> 1;              // 0 or 16 (ot select)

    for (int k = tid; k < 4096; k += 256) ((u32*)W1B)[k] = ((const u32*)w1b)[k];

    bf16x8 qkf[8];
#pragma unroll
    for (int hh = 0; hh < 8; ++hh) {
        int h = wv * 8 + hh;
        qkf[hh] = *(const bf16x8*)(qk + ((size_t)(b * 128 + i0 + ln)) * 1024 + h * 32 + qd * 8);
    }
    float b2r[4];
#pragma unroll
    for (int ot = 0; ot < 4; ++ot) b2r[ot] = b2[ot * 16 + ln];

    float acc[4][16] = {};       // [s][col within lane*16] PV accum
    float dn[4][4] = {};         // [s][ot] denom partial (pre qd-reduce)
    float dd[4][3][2] = {};      // [s][d][ot-2] dis partial
    u32 pk[4][4];                // [s][r] packed bf16(E[ot0]),bf16(E[ot1])

    __syncthreads();

#pragma clang loop unroll(disable)
    for (int ps = 0; ps < 8; ++ps) {
        const int jg0 = jq * 128 + ps * 16;

        // ---- P1: sim (MFMA) -> ES; stage bdis ----
#pragma unroll
        for (int hh = 0; hh < 4; ++hh) {
            const int h0 = wv * 8 + hh * 2;
            const u16* cp = cqk + (size_t)(b * 512 + jg0 + ln) * 1024 + qd * 8;
            bf16x8 b0 = *(const bf16x8*)(cp + h0 * 32);
            bf16x8 b1 = *(const bf16x8*)(cp + (h0 + 1) * 32);
            f32x4 c0 = (f32x4){0.f, 0.f, 0.f, 0.f}, c1 = c0;
            c0 = MFMA_BF16(qkf[hh * 2],     b0, c0, 0, 0, 0);
            c1 = MFMA_BF16(qkf[hh * 2 + 1], b1, c1, 0, 0, 0);
#pragma unroll
            for (int r = 0; r < 4; ++r) {
                u32 pv = (u32)f2bf(c0[r]) | ((u32)f2bf(c1[r]) << 16);
                *(u32*)&ES[((qd * 4 + r) * 16 + ln) * 40 + h0] = pv;
            }
        }
        {
            int jj = tid >> 4, ii = tid & 15;
            const float* sp = bdis + ((size_t)(b * 512 + jg0 + jj) * 128 + i0 + ii) * 3;
            float* dp2 = &bdisL[(jj * 16 + ii) * 4];
            dp2[0] = sp[0]; dp2[1] = sp[1]; dp2[2] = sp[2];
        }
        __syncthreads();

        // ---- P2: per s (i = i0+wv*4+s): MLP1 -> mish -> MLP2 -> E regs ----
#pragma unroll
        for (int s = 0; s < 4; ++s) {
            const int r0 = wv * 64 + s * 16;
            bf16x8 af0 = *(const bf16x8*)&ES[(r0 + ln) * 40 + qd * 8];
            bf16x8 af1;
            {   // bde channels ARE the A-frag: direct global load
                const float* dp = bde + (((size_t)(b * 512 + jg0 + ln)) * 128 + i0 + wv * 4 + s) * 32 + qd * 8;
                float4 a0 = ((const float4*)dp)[0];
                float4 a1 = ((const float4*)dp)[1];
                af1[0] = (short)f2bf(a0.x); af1[1] = (short)f2bf(a0.y);
                af1[2] = (short)f2bf(a0.z); af1[3] = (short)f2bf(a0.w);
                af1[4] = (short)f2bf(a1.x); af1[5] = (short)f2bf(a1.y);
                af1[6] = (short)f2bf(a1.z); af1[7] = (short)f2bf(a1.w);
            }
            f32x4 uacc[4];
#pragma unroll
            for (int ot = 0; ot < 4; ++ot) uacc[ot] = (f32x4){0.f, 0.f, 0.f, 0.f};
            u16* mt = &miniT[wv][0];
#pragma unroll
            for (int cg = 0; cg < 4; ++cg) {
                bf16x8 w00 = *(const bf16x8*)&W1B[((cg * 2 + 0) * 64 + lane) * 8];
                bf16x8 w01 = *(const bf16x8*)&W1B[((cg * 2 + 1) * 64 + lane) * 8];
                bf16x8 w10 = *(const bf16x8*)&W1B[((8 + cg * 2 + 0) * 64 + lane) * 8];
                bf16x8 w11 = *(const bf16x8*)&W1B[((8 + cg * 2 + 1) * 64 + lane) * 8];
                f32x4 t0 = (f32x4){0.f, 0.f, 0.f, 0.f}, t1 = t0;
                t0 = MFMA_BF16(af0, w00, t0, 0, 0, 0);
                t0 = MFMA_BF16(af1, w10, t0, 0, 0, 0);
                t1 = MFMA_BF16(af0, w01, t1, 0, 0, 0);
                t1 = MFMA_BF16(af1, w11, t1, 0, 0, 0);
#pragma unroll
                for (int r = 0; r < 4; ++r) {
                    mt[(qd * 4 + r) * 40 + ln]      = f2bf(mishf(t0[r]));
                    mt[(qd * 4 + r) * 40 + 16 + ln] = f2bf(mishf(t1[r]));
                }
                bf16x8 ta = *(const bf16x8*)&mt[ln * 40 + qd * 8];
#pragma unroll
                for (int ot = 0; ot < 4; ++ot) {
                    bf16x8 wf = *(const bf16x8*)(w2b + ((size_t)(cg * 4 + ot) * 64 + lane) * 8);
                    uacc[ot] = MFMA_BF16(ta, wf, uacc[ot], 0, 0, 0);
                }
            }
            float Ev[4][4];
#pragma unroll
            for (int ot = 0; ot < 4; ++ot) {
#pragma unroll
                for (int r = 0; r < 4; ++r) Ev[ot][r] = __expf(uacc[ot][r] + b2r[ot]);
                dn[s][ot] += Ev[ot][0] + Ev[ot][1] + Ev[ot][2] + Ev[ot][3];
            }
#pragma unroll
            for (int r = 0; r < 4; ++r) {
                pk[s][r] = (u32)f2bf(Ev[0][r]) | ((u32)f2bf(Ev[1][r]) << 16);
                const float* bp = &bdisL[((qd * 4 + r) * 16 + wv * 4 + s) * 4];
#pragma unroll
                for (int d = 0; d < 3; ++d) {
                    dd[s][d][0] += Ev[2][r] * bp[d];
                    dd[s][d][1] += Ev[3][r] * bp[d];
                }
            }
        }
        __syncthreads();

        // ---- P3: PV — bpermute E broadcast + contiguous cv rows ----
#pragma clang loop unroll(disable)
        for (int jb = 0; jb < 4; ++jb) {
#pragma unroll
            for (int jj = 0; jj < 4; ++jj) {
                const int j = jb * 4 + jj;
                const u16* cvp = cv + (size_t)(b * 512 + jg0 + j) * 1024 + lane * 16;
                uint4 v0 = *(const uint4*)cvp;
                uint4 v1 = *(const uint4*)(cvp + 8);
                float cf[16];
                cf[0]  = bflo(v0.x); cf[1]  = bfhi(v0.x);
                cf[2]  = bflo(v0.y); cf[3]  = bfhi(v0.y);
                cf[4]  = bflo(v0.z); cf[5]  = bfhi(v0.z);
                cf[6]  = bflo(v0.w); cf[7]  = bfhi(v0.w);
                cf[8]  = bflo(v1.x); cf[9]  = bfhi(v1.x);
                cf[10] = bflo(v1.y); cf[11] = bfhi(v1.y);
                cf[12] = bflo(v1.z); cf[13] = bfhi(v1.z);
                cf[14] = bflo(v1.w); cf[15] = bfhi(v1.w);
                const int idx = jb * 64 + srcbase;
#pragma unroll
                for (int s = 0; s < 4; ++s) {
                    u32 pv = (u32)__builtin_amdgcn_ds_bpermute(idx, (int)pk[s][jj]);
                    float e = __builtin_bit_cast(float, (pv >> sh) << 16);
#pragma unroll
                    for (int k = 0; k < 16; ++k) acc[s][k] += e * cf[k];
                }
            }
        }
    }

    // ---- epilogue: write partials ----
    float* P = partial + (size_t)blk * 18944;
#pragma unroll
    for (int s = 0; s < 4; ++s)
#pragma unroll
        for (int q = 0; q < 4; ++q) {
            float4 o = make_float4(acc[s][q * 4], acc[s][q * 4 + 1], acc[s][q * 4 + 2], acc[s][q * 4 + 3]);
            *(float4*)&P[(size_t)(wv * 4 + s) * 1024 + lane * 16 + q * 4] = o;
        }
#pragma unroll
    for (int s = 0; s < 4; ++s)
#pragma unroll
        for (int ot = 0; ot < 4; ++ot) {
            float v = dn[s][ot];
            v += __shfl_xor(v, 16, 64);
            v += __shfl_xor(v, 32, 64);
            if (qd == 0) P[16384 + (wv * 4 + s) * 64 + ot * 16 + ln] = v;
        }
#pragma unroll
    for (int s = 0; s < 4; ++s)
#pragma unroll
        for (int d = 0; d < 3; ++d)
#pragma unroll
            for (int o = 0; o < 2; ++o) {
                float v = dd[s][d][o];
                v += __shfl_xor(v, 16, 64);
                v += __shfl_xor(v, 32, 64);
                if (qd == 0) P[17408 + (wv * 4 + s) * 96 + d * 32 + o * 16 + ln] = v;
            }
}

// ---------------------------------------------------------------------------
// finalize: per (b,it): combine 4 jq partials, normalize, Wo epilogue (MFMA),
// dis-MLP. 128 blocks x 256 threads.
// ---------------------------------------------------------------------------
__global__ __launch_bounds__(256, 2) void finalize(
    const float* __restrict__ partial, const u16* __restrict__ WoT,
    const float* __restrict__ bo,
    const float* __restrict__ Wd1, const float* __restrict__ bd1,
    const float* __restrict__ Wd2, const float* __restrict__ bd2,
    float* __restrict__ out0, float* __restrict__ out1)
{
    __shared__ float denomL[1024];
    __shared__ u16 preL[16 * 1032];
    __shared__ float odisL[1536];
    __shared__ float r1L[3072];

    const int tid = threadIdx.x;
    const int f = blockIdx.x;
    const int b = f >> 3, it = f & 7;
    const int row0 = b * 128 + it * 16;
    const float* P0 = partial + (size_t)(f * 4 + 0) * 18944;
    const float* P1 = partial + (size_t)(f * 4 + 1) * 18944;
    const float* P2 = partial + (size_t)(f * 4 + 2) * 18944;
    const float* P3 = partial + (size_t)(f * 4 + 3) * 18944;

    for (int k = tid; k < 1024; k += 256)
        denomL[k] = P0[16384 + k] + P1[16384 + k] + P2[16384 + k] + P3[16384 + k];
    __syncthreads();

    {
        const int h = tid >> 3;
#pragma unroll
        for (int i = 0; i < 16; ++i) {
            float4 a = *(const float4*)&P0[(size_t)i * 1024 + tid * 4];
            float4 bq = *(const float4*)&P1[(size_t)i * 1024 + tid * 4];
            float4 c = *(const float4*)&P2[(size_t)i * 1024 + tid * 4];
            float4 d = *(const float4*)&P3[(size_t)i * 1024 + tid * 4];
            float rdn = 1.f / denomL[i * 64 + h];
            u32 p0 = (u32)f2bf((a.x + bq.x + c.x + d.x) * rdn) | ((u32)f2bf((a.y + bq.y + c.y + d.y) * rdn) << 16);
            u32 p1 = (u32)f2bf((a.z + bq.z + c.z + d.z) * rdn) | ((u32)f2bf((a.w + bq.w + c.w + d.w) * rdn) << 16);
            *(uint2*)(void*)&preL[i * 1032 + tid * 4] = make_uint2(p0, p1);
        }
    }
    for (int idx = tid; idx < 1536; idx += 256) {
        int i = idx / 96, rm = idx % 96, h = rm & 31;
        odisL[idx] = (P0[17408 + idx] + P1[17408 + idx] + P2[17408 + idx] + P3[17408 + idx])
                     / denomL[i * 64 + 32 + h];
    }
    __syncthreads();

    {
        const int lane = tid & 63, wv = tid >> 6;
        const int qd = lane >> 4, ln = lane & 15;
        f32x4 acc[4];
#pragma unroll
        for (int nt = 0; nt < 4; ++nt) acc[nt] = (f32x4){0.f, 0.f, 0.f, 0.f};
#pragma clang loop unroll(disable)
        for (int ks = 0; ks < 32; ++ks) {
            bf16x8 af = *(const bf16x8*)&preL[ln * 1032 + ks * 32 + qd * 8];
#pragma unroll
            for (int nt = 0; nt < 4; ++nt) {
                bf16x8 wf = *(const bf16x8*)(WoT + ((size_t)(wv * 64 + nt * 16 + ln)) * 1024 + ks * 32 + qd * 8);
                acc[nt] = MFMA_BF16(af, wf, acc[nt], 0, 0, 0);
            }
        }
#pragma unroll
        for (int nt = 0; nt < 4; ++nt) {
            int col = wv * 64 + nt * 16 + ln;
            float bv = bo[col];
#pragma unroll
            for (int r = 0; r < 4; ++r)
                out0[(size_t)(row0 + qd * 4 + r) * 256 + col] = acc[nt][r] + bv;
        }
    }

    for (int idx = tid; idx < 3072; idx += 256) {
        int i = idx / 192, rm = idx % 192, d = rm / 64, c = rm & 63;
        float t = bd1[c];
#pragma unroll
        for (int hh = 0; hh < 32; ++hh)
            t += odisL[i * 96 + d * 32 + hh] * Wd1[hh * 64 + c];
        r1L[idx] = mishf(t);
    }
    __syncthreads();
    for (int idx = tid; idx < 1536; idx += 256) {
        int i = idx / 96, rm = idx % 96, d = rm >> 5, h = rm & 31;
        float v = bd2[h];
#pragma unroll
        for (int c = 0; c < 64; ++c)
            v += r1L[i * 192 + d * 64 + c] * Wd2[c * 32 + h];
        out1[(size_t)(row0 + i) * 96 + d * 32 + h] = v;
    }
}

extern "C" void kernel_launch(void* const* d_in, const int* in_sizes, int n_in,
                              void* d_out, int out_size, void* d_ws, size_t ws_size,
                              hipStream_t stream) {
    const float* x    = (const float*)d_in[0];
    const float* ctx  = (const float*)d_in[1];
    const float* bdis = (const float*)d_in[2];
    const float* bde  = (const float*)d_in[3];
    const float* Wqk  = (const float*)d_in[6];
    const float* Wcqk = (const float*)d_in[8];
    const float* Wcv  = (const float*)d_in[9];
    const float* Wm1  = (const float*)d_in[10];
    const float* Wm2  = (const float*)d_in[11];
    const float* bm2  = (const float*)d_in[12];
    const float* Wo   = (const float*)d_in[13];
    const float* bo   = (const float*)d_in[14];
    const float* Wd1  = (const float*)d_in[15];
    const float* bd1  = (const float*)d_in[16];
    const float* Wd2  = (const float*)d_in[17];
    const float* bd2  = (const float*)d_in[18];

    char* ws = (char*)d_ws;
    u16* qk_ws  = (u16*)(ws);                       // 4 MB
    u16* cqk_ws = (u16*)(ws + 4194304);             // 16 MB
    u16* cv_ws  = (u16*)(ws + 20971520);            // 16 MB
    u16* w1b    = (u16*)(ws + 37748736);            // 16 KB
    u16* w2b    = (u16*)(ws + 37765120);            // 16 KB
    u16* WoT    = (u16*)(ws + 37781504);            // 512 KB
    float* part = (float*)(ws + 38305792);          // 512*18944*4 = 38.8 MB

    float* out0 = (float*)d_out;
    float* out1 = out0 + (size_t)2048 * 256;

    const float SCALE = 0.17677669529663687f;       // 32^-0.5, folded into qk

    prep<<<257, 256, 0, stream>>>(Wo, Wm1, Wm2, WoT, w1b, w2b);
    gemm_mfma<<<dim3(16, 16), 256, 0, stream>>>(x,   Wqk,  qk_ws,  2048, 1024, 256, SCALE);
    gemm_mfma<<<dim3(16, 64), 256, 0, stream>>>(ctx, Wcqk, cqk_ws, 8192, 1024, 256, 1.0f);
    gemm_mfma<<<dim3(16, 64), 256, 0, stream>>>(ctx, Wcv,  cv_ws,  8192, 1024, 256, 1.0f);
    attn3<<<512, 256, 0, stream>>>(qk_ws, cqk_ws, cv_ws, bde, bdis, w1b, w2b, bm2, part);
    finalize<<<128, 256, 0, stream>>>(part, WoT, bo, Wd1, bd1, Wd2, bd2, out0, out1);
}